// Round 12
// baseline (509.939 us; speedup 1.0000x reference)
//
#include <hip/hip_runtime.h>

#define TT   1024
#define NW   34          // 32-step windows; slope-1 skew offset up to 63
#define NPH  (NW + 21)   // barrier pipeline phases: NW + 3*(8 waves - 1)
#define FINF 1e30f

template<bool A> struct BoolC { static constexpr bool value = A; };

// dirs layout (bit format as baseline, keyed by 64-row band):
//   uint2 {ne2_mask, diag_mask} at ((b*16+bi)*NW + T)*64 + rr
//   bit k of window T = col 32T - o + k, o = skew lane of row rr:
//   o = (bi&1)*32 + (rr>>1)  [8 waves x 128 rows, 2 rows/lane, slope-1]
// ne2: dir != left. diag: dir == diag (first-min argmin).

__device__ __forceinline__ float dpp_shr1_old(float oldv, float x) {
    return __int_as_float(__builtin_amdgcn_update_dpp(
        __float_as_int(oldv), __float_as_int(x), 0x138, 0xF, 0xF, false));
}

// LDS pool (union of forward mbox and path-phase tables), byte offsets:
//   ne  [2][64][32] u32 : 0     (16384)   XOR-swizzled cols: idx = u ^ (rr&31)
//   dg  [2][64][32] u32 : 16384 (16384)
//   zd  [2][64][32] u32 : 32768 (16384)   packed (j2<<10)|jn for word-zero case
//   psh [2][64] float2  : 49152 (1024)
//   recs[160] u32       : 50176 (640)
//   nrec u32            : 50816 (4)
//   wsum[8] f32         : 50820 (32)
#define POOL_BYTES 50852
#define SWZ(rr, u) ((u) ^ ((rr) & 31))

// ---------------- fused: forward DP + in-block backtrace + loss ------------
__global__ __launch_bounds__(512) void dtw_fused(
    const float* __restrict__ preds,
    const float* __restrict__ targs,
    const float* __restrict__ subcoef,
    uint2* __restrict__ dirs,
    float* __restrict__ out)
{
    __shared__ float2 qsh[TT];
    __shared__ __align__(16) char pool[POOL_BYTES];

    float (*mbox)[TT] = (float (*)[TT])pool;   // forward-phase view (7*TT)

    const int tid  = threadIdx.x;
    const int w    = tid >> 6;
    const int lane = tid & 63;
    const int b    = blockIdx.x;

    for (int k = tid; k < TT; k += 512) {
        float4 t4 = ((const float4*)targs)[(size_t)b * TT + k];
        qsh[k] = make_float2(t4.x, t4.y);
    }
    for (int k = tid; k < 7 * TT; k += 512) ((float*)pool)[k] = FINF;

    float px0, py0, px1, py1;
    {
        const int row0 = w * 128 + 2 * lane;
        float4 pv = ((const float4*)preds)[(size_t)b * TT + row0];
        px0 = pv.x; py0 = pv.y;
        float4 pw = ((const float4*)preds)[(size_t)b * TT + row0 + 1];
        px1 = pw.x; py1 = pw.y;
    }
    __syncthreads();

    // ================== phase 1: forward DP (r6-verified body) ==============
    {
        const float* src = (w > 0) ? mbox[w - 1] : nullptr;
        float*       dst = (w < 7) ? mbox[w]     : nullptr;

        float cur0 = FINF, cur1 = FINF, uprev = FINF, ucur = FINF;
        unsigned au0 = 0, ad0 = 0, au1 = 0, ad1 = 0;
        unsigned pau0 = 0, pad0 = 0, pau1 = 0, pad1 = 0;
        int pT = -1;

        const int bi  = 2 * w + (lane >> 5);
        const int rr0 = 2 * (lane & 31);
        const bool is63 = (lane == 63);

        for (int G = 0; G < NPH; ++G) {
            if (pT >= 0) {
                const size_t base = (size_t)((b * 16 + bi) * NW + pT) * 64 + rr0;
                *(uint4*)&dirs[base] =
                    make_uint4(__builtin_bitreverse32(pau0), __builtin_bitreverse32(pad0),
                               __builtin_bitreverse32(pau1), __builtin_bitreverse32(pad1));
                pT = -1;
            }
            const int T = G - 3 * w;
            if ((unsigned)T < (unsigned)NW) {
                float bnd[33];
#pragma unroll
                for (int k = 0; k < 33; ++k) bnd[k] = FINF;
                if (w > 0) {
#pragma unroll
                    for (int k = 0; k < 33; ++k) {
                        const int c = 32 * T + k;
                        if (c < TT) bnd[k] = src[c];
                    }
                }
                if (T == 0) ucur = bnd[0];
                float qx[32], qy[32];
#pragma unroll
                for (int k = 0; k < 32; ++k) {
                    float2 v = qsh[(32 * T + k - lane) & (TT - 1)];
                    qx[k] = v.x; qy[k] = v.y;
                }
                float bq[32];
                auto body = [&](auto actc) {
                    constexpr bool ACT = decltype(actc)::value;
#pragma unroll
                    for (int k2 = 0; k2 < 32; ++k2) {
                        const int s = 32 * T + k2;
                        const float dx0 = px0 - qx[k2], dy0 = py0 - qy[k2];
                        const float d0 = __builtin_amdgcn_sqrtf(dx0 * dx0 + dy0 * dy0);
                        const float dx1 = px1 - qx[k2], dy1 = py1 - qy[k2];
                        const float d1 = __builtin_amdgcn_sqrtf(dx1 * dx1 + dy1 * dy1);

                        const float u = ucur;
                        float ba0 = fminf(fminf(u, cur0), uprev);
                        const unsigned bd0 = (uprev == ba0) ? 1u : 0u;
                        const unsigned bu0 = ((u <= cur0) ? 1u : 0u) | bd0;
                        if constexpr (ACT) ba0 = (ba0 > 9e29f) ? 0.0f : ba0;
                        const float v0 = d0 + ba0;
                        const float ba1 = fminf(fminf(v0, cur1), cur0);
                        const unsigned bd1 = (cur0 == ba1) ? 1u : 0u;
                        const unsigned bu1 = ((v0 <= cur1) ? 1u : 0u) | bd1;
                        const float v1 = d1 + ba1;

                        au0 = au0 + au0 + bu0;  ad0 = ad0 + ad0 + bd0;
                        au1 = au1 + au1 + bu1;  ad1 = ad1 + ad1 + bd1;

                        if constexpr (ACT) {
                            const bool act = (lane <= s);
                            cur0 = act ? v0 : cur0;
                            cur1 = act ? v1 : cur1;
                        } else {
                            cur0 = v0; cur1 = v1;
                        }
                        uprev = u;
                        bq[k2] = cur1;
                        ucur = dpp_shr1_old(bnd[k2 + 1], cur1);
                    }
                };
                if (T < 2) body(BoolC<true>{}); else body(BoolC<false>{});

                if (is63 && w < 7) {
#pragma unroll
                    for (int k2 = 0; k2 < 32; ++k2) {
                        const int c = 32 * T + k2 - 63;
                        if ((unsigned)c < 1024u) dst[c] = bq[k2];
                    }
                }
                pau0 = au0; pad0 = ad0; pau1 = au1; pad1 = ad1; pT = T;
                au0 = ad0 = au1 = ad1 = 0u;
            }
            __syncthreads();
        }
        if (pT >= 0) {
            const size_t base = (size_t)((b * 16 + bi) * NW + pT) * 64 + rr0;
            *(uint4*)&dirs[base] =
                make_uint4(__builtin_bitreverse32(pau0), __builtin_bitreverse32(pad0),
                           __builtin_bitreverse32(pau1), __builtin_bitreverse32(pad1));
        }
    }
    __syncthreads();   // drain all waves' dirs stores; mbox is dead from here

    // ================== phase 2: backtrace + loss (in-block) ================
    unsigned (*ne)[64][32] = (unsigned (*)[64][32])(pool);
    unsigned (*dg)[64][32] = (unsigned (*)[64][32])(pool + 16384);
    unsigned (*zd)[64][32] = (unsigned (*)[64][32])(pool + 32768);
    float2 (*psh)[64]      = (float2 (*)[64])(pool + 49152);
    unsigned* recs         = (unsigned*)(pool + 50176);
    unsigned* nrecp        = (unsigned*)(pool + 50816);
    float* wsum            = (float*)(pool + 50820);

    // stage band -> buf: wave1 realigns (1 row/lane, serial u: builds zd run
    // in the same pass, no extra barrier); wave2 stages psh (preds rows).
    auto stage = [&](int band, int buf) {
        if (tid >= 64 && tid < 128) {
            const int rr = tid - 64;
            const size_t gbase = (size_t)(b * 16 + band) * (NW * 64);
            const int o  = ((band & 1) << 5) + (rr >> 1);
            const int sh = o & 31;
            const int Tb = o >> 5;
            unsigned run = 0;     // (j2=0)<<10 | (jn=0): no set bit below
#pragma unroll 4
            for (int u = 0; u < 32; ++u) {
                uint2 A  = dirs[gbase + (size_t)(u + Tb) * 64 + rr];
                uint2 Bv = dirs[gbase + (size_t)(u + Tb + 1) * 64 + rr];
                const unsigned nw = sh ? ((A.x >> sh) | (Bv.x << (32 - sh))) : A.x;
                const unsigned dw = sh ? ((A.y >> sh) | (Bv.y << (32 - sh))) : A.y;
                ne[buf][rr][SWZ(rr, u)] = nw;
                dg[buf][rr][SWZ(rr, u)] = dw;
                zd[buf][rr][SWZ(rr, u)] = run;
                if (nw != 0u) {
                    const int bit = 31 - __builtin_clz(nw);
                    const int c = (u << 5) + bit;
                    int jn = c - (int)((dw >> bit) & 1u);
                    if (jn < 0) jn = 0;
                    run = ((unsigned)c << 10) | (unsigned)jn;
                }
            }
        } else if (tid >= 128 && tid < 192) {
            const int rr = tid - 128;
            float4 p4 = ((const float4*)preds)[(size_t)b * TT + band * 64 + rr];
            psh[buf][rr] = make_float2(p4.x, p4.y);
        }
    };

    stage(15, 0);
    __syncthreads();

    const float sc0 = subcoef[0], sc1 = subcoef[1];
    float acc = 0.0f;
    int j = TT - 1;
    int cur = 0;

    for (int band = 15; band >= 0; --band) {
        if (w == 0) {
            // true-path walk (wave0, lane-redundant; LDS reads broadcast)
            int nrec = 0;
#pragma unroll 1
            for (int rr = 63; rr >= 0; --rr) {
                int j2, jn;
                if (band == 0 && rr == 0) { j2 = 0; jn = 0; }
                else {
                    const int u = j >> 5, m = j & 31;
                    const unsigned nw = ne[cur][rr][SWZ(rr, u)];
                    const unsigned dw = dg[cur][rr][SWZ(rr, u)];
                    const unsigned z  = zd[cur][rr][SWZ(rr, u)];
                    const unsigned wv = nw << (31 - m);
                    if (wv != 0u) {
                        j2 = (u << 5) + m - __builtin_clz(wv);
                        jn = j2 - (int)((dw >> (j2 & 31)) & 1u);
                        if (jn < 0) jn = 0;
                    } else {
                        j2 = (int)(z >> 10);
                        jn = (int)(z & 1023u);
                    }
                }
                int c = j;
                for (;;) {
                    const int cl = (c - 31 > j2) ? (c - 31) : j2;
                    if (lane == 0)
                        recs[nrec] = ((unsigned)rr << 20) | ((unsigned)cl << 10) | (unsigned)c;
                    ++nrec;
                    if (cl == j2) break;
                    c = cl - 1;
                }
                j = jn;
            }
            if (lane == 0) *nrecp = (unsigned)nrec;
        } else if (band > 0) {
            stage(band - 1, cur ^ 1);   // overlap next-band staging
        }
        __syncthreads();

        const int nr = (int)*nrecp;
        const float2* pb = psh[cur];
        for (int k = tid; k < nr; k += 512) {
            const unsigned rec = recs[k];
            const int rr = (int)(rec >> 20);
            const int cl = (int)((rec >> 10) & 1023u);
            const int ch = (int)(rec & 1023u);
            const float2 p = pb[rr];
            for (int c = cl; c <= ch; ++c) {
                const float2 q = qsh[c];
                acc += fabsf(p.x - q.x) * sc0 + fabsf(p.y - q.y) * sc1;
            }
        }
        __syncthreads();
        cur ^= 1;
    }

    for (int o = 32; o; o >>= 1) acc += __shfl_down(acc, o);
    if (lane == 0) wsum[w] = acc;
    __syncthreads();
    if (tid == 0) {
        float s = 0.0f;
#pragma unroll
        for (int k = 0; k < 8; ++k) s += wsum[k];
        atomicAdd(out, s);
    }
}

extern "C" void kernel_launch(void* const* d_in, const int* in_sizes, int n_in,
                              void* d_out, int out_size, void* d_ws, size_t ws_size,
                              hipStream_t stream)
{
    const float* preds   = (const float*)d_in[0];
    const float* targs   = (const float*)d_in[1];
    const float* subcoef = (const float*)d_in[2];
    float* out = (float*)d_out;

    const int B = in_sizes[0] / (TT * 4);

    uint2* dirs = (uint2*)d_ws;   // B*16*NW*64*8 B ~ 17.8 MB scratch

    hipMemsetAsync(out, 0, sizeof(float), stream);
    dtw_fused<<<dim3(B), dim3(512), 0, stream>>>(preds, targs, subcoef, dirs, out);
}

// Round 13
// 402.416 us; speedup vs baseline: 1.2672x; 1.2672x over previous
//
#include <hip/hip_runtime.h>

#define TT   1024
#define NW   34          // 32-step windows; slope-1 skew offset up to 63
#define NPH  (NW + 21)   // barrier pipeline phases: NW + 3*(8 waves - 1)
#define FINF 1e30f

template<bool A> struct BoolC { static constexpr bool value = A; };

// dirs layout (bit format as baseline, keyed by 64-row band):
//   uint2 {ne2_mask, diag_mask} at ((b*16+bi)*NW + T)*64 + rr
//   bit k of window T = col 32T - o + k, o = skew lane of row rr:
//   o = (bi&1)*32 + (rr>>1)  [8 waves x 128 rows, 2 rows/lane, slope-1]
// ne2: dir != left. diag: dir == diag (first-min argmin).

__device__ __forceinline__ float dpp_shr1_old(float oldv, float x) {
    return __int_as_float(__builtin_amdgcn_update_dpp(
        __float_as_int(oldv), __float_as_int(x), 0x138, 0xF, 0xF, false));
}

// ---------------- K1: forward DP (r6-verified body, 233us) ------------------
__global__ __launch_bounds__(512) void dtw_forward(
    const float* __restrict__ preds,
    const float* __restrict__ targs,
    uint2* __restrict__ dirs)
{
    __shared__ float2 qsh[TT];
    __shared__ float  mbox[7][TT];

    const int tid  = threadIdx.x;
    const int w    = tid >> 6;
    const int lane = tid & 63;
    const int b    = blockIdx.x;

    for (int k = tid; k < TT; k += 512) {
        float4 t4 = ((const float4*)targs)[(size_t)b * TT + k];
        qsh[k] = make_float2(t4.x, t4.y);
    }
    for (int k = tid; k < 7 * TT; k += 512) ((float*)mbox)[k] = FINF;

    float px0, py0, px1, py1;
    {
        const int row0 = w * 128 + 2 * lane;
        float4 pv = ((const float4*)preds)[(size_t)b * TT + row0];
        px0 = pv.x; py0 = pv.y;
        float4 pw = ((const float4*)preds)[(size_t)b * TT + row0 + 1];
        px1 = pw.x; py1 = pw.y;
    }
    __syncthreads();

    const float* src = (w > 0) ? mbox[w - 1] : nullptr;
    float*       dst = (w < 7) ? mbox[w]     : nullptr;

    float cur0 = FINF, cur1 = FINF, uprev = FINF, ucur = FINF;
    unsigned au0 = 0, ad0 = 0, au1 = 0, ad1 = 0;
    unsigned pau0 = 0, pad0 = 0, pau1 = 0, pad1 = 0;
    int pT = -1;

    const int bi  = 2 * w + (lane >> 5);
    const int rr0 = 2 * (lane & 31);
    const bool is63 = (lane == 63);

    for (int G = 0; G < NPH; ++G) {
        if (pT >= 0) {
            const size_t base = (size_t)((b * 16 + bi) * NW + pT) * 64 + rr0;
            *(uint4*)&dirs[base] =
                make_uint4(__builtin_bitreverse32(pau0), __builtin_bitreverse32(pad0),
                           __builtin_bitreverse32(pau1), __builtin_bitreverse32(pad1));
            pT = -1;
        }
        const int T = G - 3 * w;
        if ((unsigned)T < (unsigned)NW) {
            float bnd[33];
#pragma unroll
            for (int k = 0; k < 33; ++k) bnd[k] = FINF;
            if (w > 0) {
#pragma unroll
                for (int k = 0; k < 33; ++k) {
                    const int c = 32 * T + k;
                    if (c < TT) bnd[k] = src[c];
                }
            }
            if (T == 0) ucur = bnd[0];
            float qx[32], qy[32];
#pragma unroll
            for (int k = 0; k < 32; ++k) {
                float2 v = qsh[(32 * T + k - lane) & (TT - 1)];
                qx[k] = v.x; qy[k] = v.y;
            }
            float bq[32];
            auto body = [&](auto actc) {
                constexpr bool ACT = decltype(actc)::value;
#pragma unroll
                for (int k2 = 0; k2 < 32; ++k2) {
                    const int s = 32 * T + k2;
                    const float dx0 = px0 - qx[k2], dy0 = py0 - qy[k2];
                    const float d0 = __builtin_amdgcn_sqrtf(dx0 * dx0 + dy0 * dy0);
                    const float dx1 = px1 - qx[k2], dy1 = py1 - qy[k2];
                    const float d1 = __builtin_amdgcn_sqrtf(dx1 * dx1 + dy1 * dy1);

                    const float u = ucur;
                    float ba0 = fminf(fminf(u, cur0), uprev);
                    const unsigned bd0 = (uprev == ba0) ? 1u : 0u;
                    const unsigned bu0 = ((u <= cur0) ? 1u : 0u) | bd0;
                    if constexpr (ACT) ba0 = (ba0 > 9e29f) ? 0.0f : ba0;
                    const float v0 = d0 + ba0;
                    const float ba1 = fminf(fminf(v0, cur1), cur0);
                    const unsigned bd1 = (cur0 == ba1) ? 1u : 0u;
                    const unsigned bu1 = ((v0 <= cur1) ? 1u : 0u) | bd1;
                    const float v1 = d1 + ba1;

                    au0 = au0 + au0 + bu0;  ad0 = ad0 + ad0 + bd0;
                    au1 = au1 + au1 + bu1;  ad1 = ad1 + ad1 + bd1;

                    if constexpr (ACT) {
                        const bool act = (lane <= s);
                        cur0 = act ? v0 : cur0;
                        cur1 = act ? v1 : cur1;
                    } else {
                        cur0 = v0; cur1 = v1;
                    }
                    uprev = u;
                    bq[k2] = cur1;
                    ucur = dpp_shr1_old(bnd[k2 + 1], cur1);
                }
            };
            if (T < 2) body(BoolC<true>{}); else body(BoolC<false>{});

            if (is63 && w < 7) {
#pragma unroll
                for (int k2 = 0; k2 < 32; ++k2) {
                    const int c = 32 * T + k2 - 63;
                    if ((unsigned)c < 1024u) dst[c] = bq[k2];
                }
            }
            pau0 = au0; pad0 = ad0; pau1 = au1; pad1 = ad1; pT = T;
            au0 = ad0 = au1 = ad1 = 0u;
        }
        __syncthreads();
    }
    if (pT >= 0) {
        const size_t base = (size_t)((b * 16 + bi) * NW + pT) * 64 + rr0;
        *(uint4*)&dirs[base] =
            make_uint4(__builtin_bitreverse32(pau0), __builtin_bitreverse32(pad0),
                       __builtin_bitreverse32(pau1), __builtin_bitreverse32(pad1));
    }
}

// ---------------- K2: exit-only per-band walk, O(1) row-step ----------------
// prevnz[rr][u] = largest u' <= u with nebit[rr][u'] != 0 (else -1) turns the
// divergent while-scan into a constant-cost lookup (wave row-step = max over
// lanes was heavy-tailed on long left-runs).
__global__ __launch_bounds__(1024) void dtw_exits(
    const uint2* __restrict__ dirs,
    unsigned short* __restrict__ exitc)
{
    __shared__ uint2 raw[NW * 64];
    __shared__ unsigned nebit[64][32];
    __shared__ unsigned dgbit[64][32];
    __shared__ short prevnz[64][32];

    const int tid = threadIdx.x;
    const int b = blockIdx.x >> 4, bi = blockIdx.x & 15;

    for (int i = tid; i < NW * 64; i += 1024)
        raw[i] = dirs[(size_t)(b * 16 + bi) * (NW * 64) + i];
    __syncthreads();
    for (int i = tid; i < 64 * 32; i += 1024) {
        const int rr = i >> 5, u = i & 31;
        const int o  = ((bi & 1) << 5) + (rr >> 1);
        const int T0 = u + (o >> 5), sh = o & 31;
        uint2 A  = raw[T0 * 64 + rr];
        uint2 Bv = raw[(T0 + 1) * 64 + rr];
        nebit[rr][u] = sh ? ((A.x >> sh) | (Bv.x << (32 - sh))) : A.x;
        dgbit[rr][u] = sh ? ((A.y >> sh) | (Bv.y << (32 - sh))) : A.y;
    }
    __syncthreads();
    if (tid < 64) {               // per-row prev-nonzero-word table
        int p = -1;
        for (int u = 0; u < 32; ++u) {
            if (nebit[tid][u] != 0u) p = u;
            prevnz[tid][u] = (short)p;
        }
    }
    __syncthreads();

    int j = tid;
    for (int rr = 63; rr >= 0; --rr) {
        if (bi == 0 && rr == 0) { j = 0; break; }
        const int u = j >> 5, m = j & 31;
        const unsigned wv = nebit[rr][u] << (31 - m);
        int j2;
        if (wv != 0u) j2 = (u << 5) + m - __builtin_clz(wv);
        else {
            const int u2 = (u > 0) ? (int)prevnz[rr][u - 1] : -1;
            j2 = (u2 < 0) ? 0 : ((u2 << 5) + 31 - __builtin_clz(nebit[rr][u2]));
        }
        const int diag = (int)((dgbit[rr][j2 >> 5] >> (j2 & 31)) & 1u);
        j = j2 - diag;
        if (j < 0) j = 0;   // safety net (unreachable on correct dirs)
    }
    exitc[((size_t)(b * 16 + bi) << 10) + tid] = (unsigned short)j;
}

// ---------------- K3: loss replay (stitch folded in, O(1) row-step) --------
__global__ __launch_bounds__(64) void dtw_loss(
    const float* __restrict__ preds,
    const float* __restrict__ targs,
    const float* __restrict__ subcoef,
    const uint2* __restrict__ dirs,
    const unsigned short* __restrict__ exitc,
    float* __restrict__ out)
{
    __shared__ uint2 raw[NW * 64];
    __shared__ unsigned nebit[64][32];
    __shared__ unsigned dgbit[64][32];
    __shared__ short prevnz[64][32];
    __shared__ float2 qsh[TT];
    __shared__ float2 psh[64];
    __shared__ unsigned recs[160];

    const int lane = threadIdx.x;
    const int b = blockIdx.x >> 4, bi = blockIdx.x & 15;

    for (int i = lane; i < NW * 64; i += 64)
        raw[i] = dirs[(size_t)(b * 16 + bi) * (NW * 64) + i];
    for (int k = lane; k < TT; k += 64) {
        float4 t4 = ((const float4*)targs)[(size_t)b * TT + k];
        qsh[k] = make_float2(t4.x, t4.y);
    }
    {
        float4 p4 = ((const float4*)preds)[(size_t)b * TT + bi * 64 + lane];
        psh[lane] = make_float2(p4.x, p4.y);
    }
    __syncthreads();
    for (int i = lane; i < 64 * 32; i += 64) {
        const int rr = i >> 5, u = i & 31;
        const int o  = ((bi & 1) << 5) + (rr >> 1);
        const int T0 = u + (o >> 5), sh = o & 31;
        uint2 A  = raw[T0 * 64 + rr];
        uint2 Bv = raw[(T0 + 1) * 64 + rr];
        nebit[rr][u] = sh ? ((A.x >> sh) | (Bv.x << (32 - sh))) : A.x;
        dgbit[rr][u] = sh ? ((A.y >> sh) | (Bv.y << (32 - sh))) : A.y;
    }
    __syncthreads();
    {                              // per-row prev-nonzero-word table (row=lane)
        int p = -1;
        for (int u = 0; u < 32; ++u) {
            if (nebit[lane][u] != 0u) p = u;
            prevnz[lane][u] = (short)p;
        }
    }

    // entry col for this band: fold of exitc over bands 15..bi+1 (broadcast
    // same-address loads, <=15 dependent L2 hits)
    int j = TT - 1;
    for (int k = 15; k > bi; --k)
        j = exitc[((size_t)(b * 16 + k) << 10) + j];
    __syncthreads();

    // wave-redundant replay; lane 0 records <=32-col span chunks
    int nrec = 0;
    for (int rr = 63; rr >= 0; --rr) {
        int j2;
        if (bi == 0 && rr == 0) j2 = 0;
        else {
            const int u = j >> 5, m = j & 31;
            const unsigned wv = nebit[rr][u] << (31 - m);
            if (wv != 0u) j2 = (u << 5) + m - __builtin_clz(wv);
            else {
                const int u2 = (u > 0) ? (int)prevnz[rr][u - 1] : -1;
                j2 = (u2 < 0) ? 0 : ((u2 << 5) + 31 - __builtin_clz(nebit[rr][u2]));
            }
        }
        int c = j;
        for (;;) {
            int cl = (c - 31 > j2) ? (c - 31) : j2;
            if (lane == 0)
                recs[nrec] = ((unsigned)rr << 20) | ((unsigned)cl << 10) | (unsigned)c;
            ++nrec;
            if (cl == j2) break;
            c = cl - 1;
        }
        if (bi == 0 && rr == 0) j = 0;
        else {
            const int diag = (int)((dgbit[rr][j2 >> 5] >> (j2 & 31)) & 1u);
            j = j2 - diag;
            if (j < 0) j = 0;   // safety net (unreachable on correct dirs)
        }
    }
    __syncthreads();

    const float sc0 = subcoef[0], sc1 = subcoef[1];
    float acc = 0.0f;
    for (int k = lane; k < nrec; k += 64) {
        unsigned rec = recs[k];
        int rr = (int)(rec >> 20), cl = (int)((rec >> 10) & 1023u), ch = (int)(rec & 1023u);
        float2 p = psh[rr];
        for (int c = cl; c <= ch; ++c) {
            float2 q = qsh[c];
            acc += fabsf(p.x - q.x) * sc0 + fabsf(p.y - q.y) * sc1;
        }
    }
    for (int o = 32; o; o >>= 1) acc += __shfl_down(acc, o);
    if (lane == 0) atomicAdd(out, acc);
}

extern "C" void kernel_launch(void* const* d_in, const int* in_sizes, int n_in,
                              void* d_out, int out_size, void* d_ws, size_t ws_size,
                              hipStream_t stream)
{
    const float* preds   = (const float*)d_in[0];
    const float* targs   = (const float*)d_in[1];
    const float* subcoef = (const float*)d_in[2];
    float* out = (float*)d_out;

    const int B = in_sizes[0] / (TT * 4);

    const size_t dirsBytes = (size_t)B * 16 * NW * 64 * sizeof(uint2);        // ~17.8 MB
    uint2* dirs = (uint2*)d_ws;
    unsigned short* exitc = (unsigned short*)((char*)d_ws + dirsBytes);       // 2 MB

    hipMemsetAsync(out, 0, sizeof(float), stream);
    dtw_forward<<<dim3(B), dim3(512), 0, stream>>>(preds, targs, dirs);
    dtw_exits<<<dim3(B * 16), dim3(1024), 0, stream>>>(dirs, exitc);
    dtw_loss<<<dim3(B * 16), dim3(64), 0, stream>>>(preds, targs, subcoef, dirs, exitc, out);
}